// Round 4
// baseline (78.736 us; speedup 1.0000x reference)
//
#include <hip/hip_runtime.h>
#include <math.h>

#define NPTS 8192
#define NB 4
#define SCALE (1.0f/32.0f)
#define JSPLIT 4
#define JCH (NPTS/JSPLIT)        // 2048 b-points staged per block (32 KB LDS)
#define ISPLIT 32                // 8192 / APB
#define APB 256                  // a-points per block (4 waves x 2 tiles x 32)
#define BPD (ISPLIT*JSPLIT)      // 128 blocks per (batch,dir)
#define NBLK (NB*2*BPD)          // 1024
#define TK_INIT 0x7F7F7F7Fu

typedef _Float16 half4 __attribute__((ext_vector_type(4)));
typedef float float16 __attribute__((ext_vector_type(16)));
typedef unsigned long long u64;
typedef unsigned int u32;
union H4 { half4 h; u64 u; };

// ws layout (single 0x7F memset covers all):
//   [0, 256K)        minbits u32[NB][2][NPTS]   (init 0x7F7F7F7F = +3.39e38)
//   [256K, +32)      hm float[8]                (plain-stored by reducers)
//   [256K+32, +32)   tk u32[8]                  (tickets, count from TK_INIT)
//   [256K+64, +4)    tk2 u32                    (global ticket)

__device__ __forceinline__ u32 agent_load_u32(const u32* p) {
    return __hip_atomic_load(p, __ATOMIC_RELAXED, __HIP_MEMORY_SCOPE_AGENT);
}
__device__ __forceinline__ float agent_load_f32(const float* p) {
    return __hip_atomic_load(p, __ATOMIC_RELAXED, __HIP_MEMORY_SCOPE_AGENT);
}

// Two-term f16 split of the b-side Gram vector: u = -2*b', w = |b'|^2.
// K=8 terms: [uxh,uxl,uxh,uyh | uyl,uyh,wh,wl] dotted with a-side
//            [axh,axh,axl,ayh | ayh,ayl, 1, 1]  =  d2' - a2'
__device__ __forceinline__ void bsplit(float x, float y, u64& lo, u64& hi) {
    float xs = x * SCALE, ys = y * SCALE;
    float ux = -2.0f * xs, uy = -2.0f * ys;
    _Float16 uxh = (_Float16)ux; _Float16 uxl = (_Float16)(ux - (float)uxh);
    _Float16 uyh = (_Float16)uy; _Float16 uyl = (_Float16)(uy - (float)uyh);
    float w = fmaf(xs, xs, ys * ys);
    _Float16 wh = (_Float16)w;  _Float16 wl = (_Float16)(w - (float)wh);
    H4 l, h;
    l.h = (half4){uxh, uxl, uxh, uyh};
    h.h = (half4){uyl, uyh, wh, wl};
    lo = l.u; hi = h.u;
}

// 16-input min tree folded into mn: 8 x v_min3_f32 after fusion
__device__ __forceinline__ float fold16(const float16& a, float mn) {
    float m0 = fminf(fminf(a[0],  a[1]),  a[2]);
    float m1 = fminf(fminf(a[3],  a[4]),  a[5]);
    float m2 = fminf(fminf(a[6],  a[7]),  a[8]);
    float m3 = fminf(fminf(a[9],  a[10]), a[11]);
    float m4 = fminf(fminf(a[12], a[13]), a[14]);
    float t0 = fminf(fminf(m0, m1), m2);
    float t1 = fminf(fminf(m3, m4), a[15]);
    return fminf(fminf(t0, t1), mn);
}

__global__ __launch_bounds__(256, 4) void haus_main(
    const float* __restrict__ pred, const float* __restrict__ targ,
    u32* __restrict__ minbits, float* __restrict__ hm,
    u32* __restrict__ tk, u32* __restrict__ tk2, float* __restrict__ out)
{
    __shared__ u64 sL[2 * JCH];          // [khalf][point], 32 KB
    __shared__ float sred[4];
    __shared__ u32 sflag;

    int bid = blockIdx.x;
    int jh   = bid & (JSPLIT-1); bid >>= 2;
    int iblk = bid & (ISPLIT-1); bid >>= 5;
    int dir  = bid & 1;          bid >>= 1;
    int batch = bid;
    int bd = batch * 2 + dir;

    int tid = threadIdx.x;
    int wave = tid >> 6, lane = tid & 63;
    int lr = lane & 31, lh = lane >> 5;

    const float* A  = dir ? targ : pred;
    const float* Bp = dir ? pred : targ;
    const float2* ain = (const float2*)A + (size_t)batch * NPTS;
    const float4* bin = (const float4*)((const float2*)Bp + (size_t)batch * NPTS)
                        + (size_t)jh * (JCH/2);

    // Stage + transform this block's 2048-point b-chunk (4 float4/thread)
    #pragma unroll
    for (int it = 0; it < JCH/512; ++it) {
        int idx = it * 256 + tid;            // float4 index (2 points)
        float4 p = bin[idx];
        u64 lo0, hi0, lo1, hi1;
        bsplit(p.x, p.y, lo0, hi0);
        bsplit(p.z, p.w, lo1, hi1);
        *(ulonglong2*)&sL[2*idx]       = make_ulonglong2(lo0, lo1);
        *(ulonglong2*)&sL[2*JCH/2 + 2*idx] = make_ulonglong2(hi0, hi1); // = sL[JCH + 2*idx]
    }

    // a-side fragments: wave owns 64 a-points (2 i-tiles); lane holds k-half lh
    int i0 = iblk * APB + wave * 64 + lr;    // tile0 point; tile1 = i0+32
    float2 a0 = ain[i0], a1 = ain[i0 + 32];
    float ax0 = a0.x*SCALE, ay0 = a0.y*SCALE;
    float ax1 = a1.x*SCALE, ay1 = a1.y*SCALE;
    half4 R0, R1;
    {
        _Float16 xh = (_Float16)ax0, yh = (_Float16)ay0;
        _Float16 xl = (_Float16)(ax0 - (float)xh), yl = (_Float16)(ay0 - (float)yh);
        R0 = lh ? (half4){yh, yl, (_Float16)1.0f, (_Float16)1.0f}
                : (half4){xh, xh, xl, yh};
        xh = (_Float16)ax1; yh = (_Float16)ay1;
        xl = (_Float16)(ax1 - (float)xh); yl = (_Float16)(ay1 - (float)yh);
        R1 = lh ? (half4){yh, yl, (_Float16)1.0f, (_Float16)1.0f}
                : (half4){xh, xh, xl, yh};
    }
    float a2_0 = fmaf(ax0, ax0, ay0*ay0);
    float a2_1 = fmaf(ax1, ax1, ay1*ay1);

    __syncthreads();

    const float16 z = {};
    float mn0 = 3.0e38f, mn1 = 3.0e38f;
    const u64* lp = &sL[lh * JCH + lr];

    // 64 j-tiles; 2 independent MFMA+fold chains; 1-deep L prefetch
    H4 L0; L0.u = lp[0];
    #pragma unroll 2
    for (int jt = 0; jt < JCH/32 - 1; ++jt) {
        H4 Ln; Ln.u = lp[(jt + 1) * 32];
        float16 acc0 = __builtin_amdgcn_mfma_f32_32x32x8f16(L0.h, R0, z, 0, 0, 0);
        float16 acc1 = __builtin_amdgcn_mfma_f32_32x32x8f16(L0.h, R1, z, 0, 0, 0);
        mn0 = fold16(acc0, mn0);
        mn1 = fold16(acc1, mn1);
        L0 = Ln;
    }
    {
        float16 acc0 = __builtin_amdgcn_mfma_f32_32x32x8f16(L0.h, R0, z, 0, 0, 0);
        float16 acc1 = __builtin_amdgcn_mfma_f32_32x32x8f16(L0.h, R1, z, 0, 0, 0);
        mn0 = fold16(acc0, mn0);
        mn1 = fold16(acc1, mn1);
    }

    // merge lane halves (other 16 j-rows of same a-point)
    mn0 = fminf(mn0, __shfl_xor(mn0, 32));
    mn1 = fminf(mn1, __shfl_xor(mn1, 32));

    // lh==0 lanes commit tile0, lh==1 lanes commit tile1
    u32* dst = minbits + ((size_t)bd << 13);
    float v  = lh ? fmaxf(mn1 + a2_1, 0.0f) : fmaxf(mn0 + a2_0, 0.0f);
    atomicMin(dst + i0 + 32*lh, __float_as_uint(v));

    // ---- per-(batch,dir) completion: last of 128 blocks reduces the row ----
    __threadfence();
    if (tid == 0) sflag = atomicAdd(&tk[bd], 1u);
    __syncthreads();
    if (sflag == TK_INIT + BPD - 1) {
        const u32* row = minbits + ((size_t)bd << 13);
        float m = 0.0f;
        #pragma unroll
        for (int k = 0; k < NPTS/256; ++k)
            m = fmaxf(m, __uint_as_float(agent_load_u32(row + k*256 + tid)));
        #pragma unroll
        for (int o = 32; o; o >>= 1) m = fmaxf(m, __shfl_xor(m, o));
        if (lane == 0) sred[wave] = m;
        __syncthreads();
        if (tid == 0) {
            hm[bd] = fmaxf(fmaxf(sred[0], sred[1]), fmaxf(sred[2], sred[3]));
            __threadfence();
            u32 o2 = atomicAdd(tk2, 1u);
            if (o2 == TK_INIT + NB*2 - 1) {       // 8th reducer finalizes
                __threadfence();
                float s = 0.0f;
                #pragma unroll
                for (int b = 0; b < NB; ++b) {
                    float h0 = agent_load_f32(&hm[2*b]);
                    float h1 = agent_load_f32(&hm[2*b + 1]);
                    s += sqrtf(fmaxf(h0, h1));
                }
                out[0] = s * (32.0f / NB);        // unscale + mean
            }
        }
    }
}

extern "C" void kernel_launch(void* const* d_in, const int* in_sizes, int n_in,
                              void* d_out, int out_size, void* d_ws, size_t ws_size,
                              hipStream_t stream) {
    const float* pred = (const float*)d_in[0];   // [4,8192,2] f32
    const float* targ = (const float*)d_in[1];   // [4,8192,2] f32

    u32*   minbits = (u32*)d_ws;
    float* hm      = (float*)((char*)d_ws + 262144);
    u32*   tk      = (u32*)((char*)d_ws + 262144 + 32);
    u32*   tk2     = (u32*)((char*)d_ws + 262144 + 64);

    // One fill: minbits -> +3.39e38, tickets -> TK_INIT (they count from there)
    hipMemsetAsync(d_ws, 0x7F, 262144 + 68, stream);
    hipLaunchKernelGGL(haus_main, dim3(NBLK), dim3(256), 0, stream,
                       pred, targ, minbits, hm, tk, tk2, (float*)d_out);
}

// Round 5
// 31.489 us; speedup vs baseline: 2.5005x; 2.5005x over previous
//
#include <hip/hip_runtime.h>
#include <math.h>

#define NPTS 8192
#define NB 4
#define SCALE (1.0f/32.0f)
#define JSPLIT 4
#define JCH (NPTS/JSPLIT)   // 2048 b-points staged per block (32 KB LDS)
#define NTILE (JCH/32)      // 64 j-tiles per block

typedef _Float16 half4 __attribute__((ext_vector_type(4)));
typedef float float16 __attribute__((ext_vector_type(16)));
typedef unsigned long long u64;
typedef unsigned int u32;
union H4 { half4 h; u64 u; };

// ws layout:
//   [0, 256K)   : minbits u32[NB][2][NPTS] (init by prep to 0x7F7F7F7F)
//   [1M, 2M)    : AV u64[src2][khalf2][NB][NPTS]
//   [2M, 3M)    : BV u64[src2][khalf2][NB][NPTS]

// Two-term f16 split, K=8 Gram expansion:
//   b-side [uxh,uxl,uxh,uyh | uyl,uyh,wh,wl]  (u=-2b', w=|b'|^2)
//   a-side [axh,axh,axl,ayh | ayh,ayl, 1, 1]
//   dot = -2<a',b'> + |b'|^2 = d2' - a2'
__global__ __launch_bounds__(256) void haus_prep(
    const float* __restrict__ pred, const float* __restrict__ targ,
    u64* __restrict__ AV, u64* __restrict__ BV, u32* __restrict__ minbits)
{
    int tid = blockIdx.x * 256 + threadIdx.x;       // 0..65535
    minbits[tid] = 0x7F7F7F7Fu;                     // +3.39e38 for atomicMin
    int src = tid >> 15;                            // 0=pred, 1=targ
    int idx = tid & 32767;                          // batch*NPTS + pt
    const float2* in = (const float2*)(src ? targ : pred);
    float2 p = in[idx];
    float xs = p.x * SCALE, ys = p.y * SCALE;
    _Float16 axh = (_Float16)xs; _Float16 axl = (_Float16)(xs - (float)axh);
    _Float16 ayh = (_Float16)ys; _Float16 ayl = (_Float16)(ys - (float)ayh);
    H4 alo, ahi;
    alo.h = (half4){axh, axh, axl, ayh};
    ahi.h = (half4){ayh, ayl, (_Float16)1.0f, (_Float16)1.0f};
    float ux = -2.0f * xs, uy = -2.0f * ys;
    _Float16 uxh = (_Float16)ux; _Float16 uxl = (_Float16)(ux - (float)uxh);
    _Float16 uyh = (_Float16)uy; _Float16 uyl = (_Float16)(uy - (float)uyh);
    float w = fmaf(xs, xs, ys * ys);
    _Float16 wh = (_Float16)w; _Float16 wl = (_Float16)(w - (float)wh);
    H4 blo, bhi;
    blo.h = (half4){uxh, uxl, uxh, uyh};
    bhi.h = (half4){uyl, uyh, wh, wl};
    AV[(src*2+0)*(NB*NPTS) + idx] = alo.u;
    AV[(src*2+1)*(NB*NPTS) + idx] = ahi.u;
    BV[(src*2+0)*(NB*NPTS) + idx] = blo.u;
    BV[(src*2+1)*(NB*NPTS) + idx] = bhi.u;
}

// 16-input min tree folded into mn: 8 v_min3_f32 after fusion
__device__ __forceinline__ float fold16(const float16& a, float mn) {
    float m0 = fminf(fminf(a[0],  a[1]),  a[2]);
    float m1 = fminf(fminf(a[3],  a[4]),  a[5]);
    float m2 = fminf(fminf(a[6],  a[7]),  a[8]);
    float m3 = fminf(fminf(a[9],  a[10]), a[11]);
    float m4 = fminf(fminf(a[12], a[13]), a[14]);
    float t0 = fminf(fminf(m0, m1), m2);
    float t1 = fminf(fminf(m3, m4), a[15]);
    return fminf(fminf(t0, t1), mn);
}

__global__ __launch_bounds__(256, 4) void haus_main(
    const float* __restrict__ pred, const float* __restrict__ targ,
    const u64* __restrict__ AV, const u64* __restrict__ BV,
    u32* __restrict__ minbits)
{
    __shared__ u64 sL[2 * JCH];                      // [khalf][point], 32 KB

    int bid = blockIdx.x;                            // 1024 = 4js x 32ib x 2dir x 4b
    int jh   = bid & (JSPLIT-1); bid >>= 2;
    int iblk = bid & 31;         bid >>= 5;
    int dir  = bid & 1;          bid >>= 1;
    int batch = bid;

    int tid = threadIdx.x;
    int wave = tid >> 6, lane = tid & 63;
    int lr = lane & 31, lh = lane >> 5;
    int asrc = dir, bsrc = dir ^ 1;                  // dir0: a=pred,b=targ

    // Stage this block's j-chunk of pre-transformed b-side frags (linear)
    const u64* s0 = BV + (size_t)(bsrc*2+0)*(NB*NPTS) + batch*NPTS + jh*JCH;
    const u64* s1 = BV + (size_t)(bsrc*2+1)*(NB*NPTS) + batch*NPTS + jh*JCH;
    #pragma unroll
    for (int it = 0; it < JCH/256; ++it) {
        sL[it*256 + tid]       = s0[it*256 + tid];
        sL[JCH + it*256 + tid] = s1[it*256 + tid];
    }

    // Persistent a-side frags: lane (lr,lh) holds k-half lh of its a-point
    int ibase = iblk*256 + wave*64;                  // 2 i-tiles: +0, +32
    const u64* av = AV + (size_t)(asrc*2+lh)*(NB*NPTS) + batch*NPTS;
    H4 r0u, r1u; r0u.u = av[ibase + lr]; r1u.u = av[ibase + 32 + lr];
    half4 R0 = r0u.h, R1 = r1u.h;

    __syncthreads();

    const float16 z = {};
    float mn0 = 3.0e38f, mn1 = 3.0e38f;
    const u64* lp = sL + lh*JCH + lr;

    // Software pipeline: fold of tile t overlaps MFMAs of tile t+1.
    // Two acc slots (A/B), statically named; 1-deep L prefetch.
    H4 La, Lb;
    La.u = lp[0];
    float16 aA0 = __builtin_amdgcn_mfma_f32_32x32x8f16(La.h, R0, z, 0, 0, 0);
    float16 aA1 = __builtin_amdgcn_mfma_f32_32x32x8f16(La.h, R1, z, 0, 0, 0);
    Lb.u = lp[32];
    float16 aB0, aB1;
    for (int t = 1; t < NTILE - 1; t += 2) {
        // tile t (odd) in slot B; fold tile t-1 (slot A) while B flies
        aB0 = __builtin_amdgcn_mfma_f32_32x32x8f16(Lb.h, R0, z, 0, 0, 0);
        aB1 = __builtin_amdgcn_mfma_f32_32x32x8f16(Lb.h, R1, z, 0, 0, 0);
        La.u = lp[(t + 1) * 32];
        mn0 = fold16(aA0, mn0); mn1 = fold16(aA1, mn1);
        // tile t+1 (even) in slot A; fold tile t (slot B)
        aA0 = __builtin_amdgcn_mfma_f32_32x32x8f16(La.h, R0, z, 0, 0, 0);
        aA1 = __builtin_amdgcn_mfma_f32_32x32x8f16(La.h, R1, z, 0, 0, 0);
        Lb.u = lp[(t + 2) * 32];
        mn0 = fold16(aB0, mn0); mn1 = fold16(aB1, mn1);
    }
    // tiles 0..62 issued, 0..61 folded; Lb holds tile 63's operand
    aB0 = __builtin_amdgcn_mfma_f32_32x32x8f16(Lb.h, R0, z, 0, 0, 0);
    aB1 = __builtin_amdgcn_mfma_f32_32x32x8f16(Lb.h, R1, z, 0, 0, 0);
    mn0 = fold16(aA0, mn0); mn1 = fold16(aA1, mn1);
    mn0 = fold16(aB0, mn0); mn1 = fold16(aB1, mn1);

    // merge lane halves (other 16 j-rows of the same a-point)
    mn0 = fminf(mn0, __shfl_xor(mn0, 32));
    mn1 = fminf(mn1, __shfl_xor(mn1, 32));

    if (lh == 0) {
        const float2* ain = (const float2*)(asrc ? targ : pred) + (size_t)batch*NPTS;
        u32* dst = minbits + ((batch*2 + dir) << 13);
        int i = ibase + lr;
        float2 p = ain[i];
        float xs = p.x*SCALE, ys = p.y*SCALE;
        float v = fmaxf(mn0 + fmaf(xs, xs, ys*ys), 0.0f);
        atomicMin(dst + i, __float_as_uint(v));
        p = ain[i + 32];
        xs = p.x*SCALE; ys = p.y*SCALE;
        v = fmaxf(mn1 + fmaf(xs, xs, ys*ys), 0.0f);
        atomicMin(dst + i + 32, __float_as_uint(v));
    }
}

// One block, 8 waves: wave w max-reduces row w of minbits; thread 0 finalizes.
__global__ __launch_bounds__(512) void haus_finish(
    const u32* __restrict__ minbits, float* __restrict__ out)
{
    int w = threadIdx.x >> 6, lane = threadIdx.x & 63;
    const uint4* row = (const uint4*)(minbits + ((size_t)w << 13));
    float m = 0.0f;
    #pragma unroll 8
    for (int k = 0; k < 32; ++k) {
        uint4 v = row[k * 64 + lane];
        m = fmaxf(m, fmaxf(fmaxf(__uint_as_float(v.x), __uint_as_float(v.y)),
                           fmaxf(__uint_as_float(v.z), __uint_as_float(v.w))));
    }
    #pragma unroll
    for (int o = 32; o; o >>= 1) m = fmaxf(m, __shfl_xor(m, o));
    __shared__ float sred[8];
    if (lane == 0) sred[w] = m;
    __syncthreads();
    if (threadIdx.x == 0) {
        float s = 0.0f;
        #pragma unroll
        for (int b = 0; b < NB; ++b)
            s += sqrtf(fmaxf(sred[2*b], sred[2*b + 1]));
        out[0] = s * (32.0f / NB);                   // unscale + mean
    }
}

extern "C" void kernel_launch(void* const* d_in, const int* in_sizes, int n_in,
                              void* d_out, int out_size, void* d_ws, size_t ws_size,
                              hipStream_t stream) {
    const float* pred = (const float*)d_in[0];   // [4,8192,2] f32
    const float* targ = (const float*)d_in[1];   // [4,8192,2] f32

    u32* minbits = (u32*)d_ws;
    u64* AV = (u64*)((char*)d_ws + (1u << 20));
    u64* BV = (u64*)((char*)d_ws + (2u << 20));

    hipLaunchKernelGGL(haus_prep, dim3(256), dim3(256), 0, stream,
                       pred, targ, AV, BV, minbits);
    hipLaunchKernelGGL(haus_main, dim3(NB * 2 * 32 * JSPLIT), dim3(256), 0, stream,
                       pred, targ, AV, BV, minbits);
    hipLaunchKernelGGL(haus_finish, dim3(1), dim3(512), 0, stream,
                       minbits, (float*)d_out);
}